// Round 6
// baseline (337.154 us; speedup 1.0000x reference)
//
#include <hip/hip_runtime.h>
#include <math.h>

#define D 128
#define B_SZ 1024
#define KNB 200
#define AHW 392   // [q|h|r] LDS stride (halves): 196 dw, %32=4 -> cheap 2-way pairs
#define PW 1048   // P LDS stride (halves)

typedef _Float16 half8 __attribute__((ext_vector_type(8)));
typedef float floatx4 __attribute__((ext_vector_type(4)));

__device__ __forceinline__ float sigmoid_f(float x) { return 1.f / (1.f + __expf(-x)); }
__device__ __forceinline__ float tanh_fast(float x) { return 1.f - 2.f / (__expf(2.f * x) + 1.f); }

__device__ __forceinline__ half8 h8zero() {
    half8 z;
    #pragma unroll
    for (int i = 0; i < 8; ++i) z[i] = (_Float16)0.f;
    return z;
}

// ---------------------------------------------------------------------------
// Kernel 1: gather+sum, GCN linear, support encoder, query gather.
// One block per batch row b, 512 threads. (Known wall: ~1.25 TB/s random.)
// Blocks 0..95 additionally convert the LSTM weights to fp16 (was k_cvtw):
// w16[0:131072] = w_ih [1024][128]; w16[131072:] = w_hh [1024][256].
// ---------------------------------------------------------------------------
__global__ __launch_bounds__(512) void k_support(
    const int* __restrict__ relations, const int* __restrict__ entities,
    const int* __restrict__ query, const float* __restrict__ emb,
    const float* __restrict__ gcn_w, const float* __restrict__ gcn_b,
    const float* __restrict__ p1_w, const float* __restrict__ p1_b,
    const float* __restrict__ p2_w, const float* __restrict__ p2_b,
    const float* __restrict__ ln_a, const float* __restrict__ ln_b,
    const float* __restrict__ w_ih, const float* __restrict__ w_hh,
    _Float16* __restrict__ w16,
    float* __restrict__ sg, _Float16* __restrict__ sgH, _Float16* __restrict__ sgT,
    float* __restrict__ qb, _Float16* __restrict__ qbH)
{
    __shared__ int idxs[2 * KNB];
    __shared__ __align__(16) float part[16][132];
    __shared__ __align__(16) float S[2 * D];
    __shared__ __align__(16) float sup[D];
    __shared__ __align__(16) float hid[2 * D];
    __shared__ __align__(16) float zv[D];
    __shared__ float red2[2];

    const int b = blockIdx.x;
    const int t = threadIdx.x;

    // ---- folded weight conversion (96 blocks x 512 thr x 8 floats = 393216)
    if (b < 96) {
        const int i8 = (b * 512 + t) * 8;
        const float* src = (i8 < 131072) ? (w_ih + i8) : (w_hh + (i8 - 131072));
        float4 v0 = *(const float4*)src;
        float4 v1 = *(const float4*)(src + 4);
        half8 h;
        h[0] = (_Float16)v0.x; h[1] = (_Float16)v0.y; h[2] = (_Float16)v0.z; h[3] = (_Float16)v0.w;
        h[4] = (_Float16)v1.x; h[5] = (_Float16)v1.y; h[6] = (_Float16)v1.z; h[7] = (_Float16)v1.w;
        *(half8*)&w16[i8] = h;
    }

    if (t < KNB) idxs[t] = relations[b * KNB + t];
    else if (t < 2 * KNB) idxs[t] = entities[b * KNB + (t - KNB)];
    __syncthreads();

    {
        const int g = t >> 5, c4 = (t & 31) * 4;
        const int* mi = &idxs[(g >> 3) * KNB];
        float4 a4 = make_float4(0.f, 0.f, 0.f, 0.f);
        #pragma unroll 5
        for (int k = (g & 7); k < KNB; k += 8) {
            float4 v = *(const float4*)&emb[(size_t)mi[k] * D + c4];
            a4.x += v.x; a4.y += v.y; a4.z += v.z; a4.w += v.w;
        }
        *(float4*)&part[g][c4] = a4;
    }
    __syncthreads();
    if (t < 2 * D) {
        const int half = t >> 7, c = t & 127;
        float s = 0.f;
        #pragma unroll
        for (int j = 0; j < 8; ++j) s += part[half * 8 + j][c];
        S[t] = s;
    }
    __syncthreads();

    if (t < D) {
        const float4* w4 = (const float4*)(gcn_w + t * 2 * D);
        float dot = 0.f;
        #pragma unroll 8
        for (int f = 0; f < 2 * D / 4; ++f) {
            float4 w = w4[f];
            float4 s = *(const float4*)&S[f * 4];
            dot += w.x * s.x + w.y * s.y + w.z * s.z + w.w * s.w;
        }
        float v = (dot + 200.f * gcn_b[t]) * (1.f / 1024.f);  // num_neighbors = B = 1024
        sup[t] = tanhf(v);
    }
    __syncthreads();

    if (t < 2 * D) {
        const float4* w4 = (const float4*)(p1_w + t * D);
        float dot = 0.f;
        #pragma unroll 8
        for (int f = 0; f < D / 4; ++f) {
            float4 w = w4[f];
            float4 s = *(const float4*)&sup[f * 4];
            dot += w.x * s.x + w.y * s.y + w.z * s.z + w.w * s.w;
        }
        float h = dot + p1_b[t];
        hid[t] = h > 0.f ? h : 0.f;
    }
    __syncthreads();

    if (t < D) {
        const float4* w4 = (const float4*)(p2_w + t * 2 * D);
        float dot = 0.f;
        #pragma unroll 8
        for (int f = 0; f < 2 * D / 4; ++f) {
            float4 w = w4[f];
            float4 s = *(const float4*)&hid[f * 4];
            dot += w.x * s.x + w.y * s.y + w.z * s.z + w.w * s.w;
        }
        zv[t] = dot + p2_b[t] + sup[t];
    }
    __syncthreads();

    if (t < 64) {
        float x0 = zv[t], x1 = zv[t + 64];
        float s = x0 + x1;
        for (int off = 32; off; off >>= 1) s += __shfl_down(s, off);
        float mu = __shfl(s, 0) * (1.f / 128.f);
        float d0 = x0 - mu, d1 = x1 - mu;
        float v = d0 * d0 + d1 * d1;
        for (int off = 32; off; off >>= 1) v += __shfl_down(v, off);
        v = __shfl(v, 0);
        if (t == 0) { red2[0] = mu; red2[1] = sqrtf(v * (1.f / 127.f)); }
    }
    __syncthreads();
    if (t < D) {
        float mu = red2[0], sigma = red2[1];
        float val = (zv[t] - mu) / (sigma + 1e-3f) * ln_a[t] + ln_b[t];
        sg[b * D + t] = val;
        sgH[b * D + t] = (_Float16)val;
        sgT[t * B_SZ + b] = (_Float16)val;
        float qv = emb[(size_t)query[b] * D + t];
        qb[b * D + t] = qv;
        qbH[b * D + t] = (_Float16)qv;
    }
}

// ---------------------------------------------------------------------------
// Kernel 2: FUSED recurrence. 64 blocks x 16 rows, 1024 threads (16 waves).
// waves_per_eu(4,4): 81 KB LDS caps at 1 block/CU = 4 waves/EU -> 128-VGPR
// budget, no spill (verified r4: WRITE 52MB -> 4KB).
// r4 postmortem: `unroll 1` alone made every GEMM iteration a serial
// load->vmcnt(0)->MFMA chain (~28 L2 round-trips/step exposed). This round:
// explicit register double-buffer prefetch in each streaming loop — issue
// iter ks+1's B-operands before iter ks's MFMAs, keep unroll 1 so in-flight
// destinations stay bounded (gates 32 VGPR, scores 8, r 8). Compiler then
// emits counted vmcnt(N); ~1 load latency exposed per phase.
// ---------------------------------------------------------------------------
__global__ __launch_bounds__(1024)
__attribute__((amdgpu_waves_per_eu(4, 4)))
void k_lstm(
    const _Float16* __restrict__ qbH, const float* __restrict__ qb,
    const _Float16* __restrict__ sgH, const _Float16* __restrict__ sgT,
    const float* __restrict__ sg, const _Float16* __restrict__ w16,
    const float* __restrict__ b_ih, const float* __restrict__ b_hh,
    float* __restrict__ out)
{
    __shared__ _Float16 Ah[16 * AHW];      // [row][0:128]=q, [128:256]=h, [256:384]=r
    __shared__ _Float16 P[16 * PW];        // unnormalized exp, fp16
    __shared__ float qF[16][132];          // q f32 (pointwise residual)
    __shared__ float hF[16][132];          // h f32 (for cosine)
    __shared__ float rpar[2][16][132];     // r K-half partials
    __shared__ float pred[16][17];         // [wave][row] partial max / partial sum
    __shared__ float mrow[16];
    __shared__ float sinv[16];

    const int t = threadIdx.x;
    const int w = t >> 6, lane = t & 63;
    const int m = lane & 15, quad = lane >> 4;
    const int b0 = blockIdx.x * 16;
    const int u = w * 16 + m;              // unit 0..255

    // ---- prologue: stage q (f16 into Ah[:,0:128], f32 into qF)
    if (t < 256) {
        const int row = t >> 4, c = (t & 15) * 8;
        *(half8*)&Ah[row * AHW + c] = *(const half8*)&qbH[(b0 + row) * D + c];
    }
    if (t < 512) {
        const int row = t >> 5, c = (t & 31) * 4;
        *(float4*)&qF[row][c] = *(const float4*)&qb[(b0 + row) * D + c];
    }
    float bi[4];
    #pragma unroll
    for (int g = 0; g < 4; ++g) bi[g] = b_ih[g * 256 + u] + b_hh[g * 256 + u];
    __syncthreads();

    // ---- gq = q @ w_ih^T, persistent in registers across all steps
    floatx4 gqr[4];
    #pragma unroll
    for (int g = 0; g < 4; ++g)
        #pragma unroll
        for (int z = 0; z < 4; ++z) gqr[g][z] = 0.f;
    {
        const _Float16* wq = w16 + (size_t)u * D + quad * 8;   // +g*256*D, +ks*32
        half8 cur[4], nxt[4];
        #pragma unroll
        for (int g = 0; g < 4; ++g) { cur[g] = *(const half8*)(wq + (size_t)g * 256 * D); nxt[g] = h8zero(); }
        #pragma unroll 1
        for (int ks = 0; ks < 4; ++ks) {
            if (ks < 3) {
                #pragma unroll
                for (int g = 0; g < 4; ++g)
                    nxt[g] = *(const half8*)(wq + (size_t)g * 256 * D + (ks + 1) * 32);
            }
            half8 a = *(const half8*)&Ah[m * AHW + ks * 32 + quad * 8];
            #pragma unroll
            for (int g = 0; g < 4; ++g)
                gqr[g] = __builtin_amdgcn_mfma_f32_16x16x32_f16(a, cur[g], gqr[g], 0, 0, 0);
            #pragma unroll
            for (int g = 0; g < 4; ++g) cur[g] = nxt[g];
        }
    }

    // ---- step 0 pointwise (c = 0, h_r = 0)
    float creg[4];
    #pragma unroll
    for (int rr = 0; rr < 4; ++rr) {
        float gi = gqr[0][rr] + bi[0];
        float gg = gqr[2][rr] + bi[2];
        float go = gqr[3][rr] + bi[3];
        float cn = sigmoid_f(gi) * tanh_fast(gg);
        creg[rr] = cn;
        if (w < 8) {
            const int row = quad * 4 + rr;
            float ho = qF[row][u] + sigmoid_f(go) * tanh_fast(cn);
            Ah[row * AHW + 128 + u] = (_Float16)ho;
            hF[row][u] = ho;
        }
    }
    __syncthreads();

    #pragma unroll 1
    for (int s = 0; s < 3; ++s) {
        // ---- scores: wave w -> j-tiles 4w..4w+3 (h lives at Ah[:,128:256])
        floatx4 a2[4];
        #pragma unroll
        for (int i = 0; i < 4; ++i)
            #pragma unroll
            for (int z = 0; z < 4; ++z) a2[i][z] = 0.f;
        {
            const _Float16* sb = sgH + (size_t)m * D + quad * 8;  // +j0*D, +ks*32
            half8 cur[4], nxt[4];
            #pragma unroll
            for (int i = 0; i < 4; ++i) {
                cur[i] = *(const half8*)(sb + (size_t)((w * 4 + i) * 16) * D);
                nxt[i] = h8zero();
            }
            #pragma unroll 1
            for (int ks = 0; ks < 4; ++ks) {
                if (ks < 3) {
                    #pragma unroll
                    for (int i = 0; i < 4; ++i)
                        nxt[i] = *(const half8*)(sb + (size_t)((w * 4 + i) * 16) * D + (ks + 1) * 32);
                }
                half8 a = *(const half8*)&Ah[m * AHW + 128 + ks * 32 + quad * 8];
                #pragma unroll
                for (int i = 0; i < 4; ++i)
                    a2[i] = __builtin_amdgcn_mfma_f32_16x16x32_f16(a, cur[i], a2[i], 0, 0, 0);
                #pragma unroll
                for (int i = 0; i < 4; ++i) cur[i] = nxt[i];
            }
        }

        // ---- softmax (register partials + two small LDS reductions)
        float mloc[4];
        #pragma unroll
        for (int rr = 0; rr < 4; ++rr)
            mloc[rr] = fmaxf(fmaxf(a2[0][rr], a2[1][rr]), fmaxf(a2[2][rr], a2[3][rr]));
        #pragma unroll
        for (int off = 1; off <= 8; off <<= 1)
            #pragma unroll
            for (int rr = 0; rr < 4; ++rr)
                mloc[rr] = fmaxf(mloc[rr], __shfl_xor(mloc[rr], off));
        if (m == 0) {
            #pragma unroll
            for (int rr = 0; rr < 4; ++rr) pred[w][quad * 4 + rr] = mloc[rr];
        }
        __syncthreads();
        if (t < 16) {
            float mm = -1e30f;
            #pragma unroll
            for (int ww = 0; ww < 16; ++ww) mm = fmaxf(mm, pred[ww][t]);
            mrow[t] = mm;
        }
        __syncthreads();

        float sloc[4] = {0.f, 0.f, 0.f, 0.f};
        #pragma unroll
        for (int i = 0; i < 4; ++i) {
            const int col = (w * 4 + i) * 16 + m;
            #pragma unroll
            for (int rr = 0; rr < 4; ++rr) {
                const int row = quad * 4 + rr;
                float e = __expf(a2[i][rr] - mrow[row]);
                P[row * PW + col] = (_Float16)e;
                sloc[rr] += e;
            }
        }
        #pragma unroll
        for (int off = 1; off <= 8; off <<= 1)
            #pragma unroll
            for (int rr = 0; rr < 4; ++rr)
                sloc[rr] += __shfl_xor(sloc[rr], off);
        if (m == 0) {
            #pragma unroll
            for (int rr = 0; rr < 4; ++rr) pred[w][quad * 4 + rr] = sloc[rr];
        }
        __syncthreads();
        if (t < 16) {
            float ss = 0.f;
            #pragma unroll
            for (int ww = 0; ww < 16; ++ww) ss += pred[ww][t];
            sinv[t] = 1.f / ss;
        }

        // ---- r partials: wave -> (n-tile = w&7, K-half = w>>3), depth-2 prefetch
        {
            const int nt = w & 7, kh = w >> 3;
            const _Float16* tb = sgT + (size_t)(nt * 16 + m) * B_SZ + quad * 8;  // +kk*32
            floatx4 a3;
            #pragma unroll
            for (int z = 0; z < 4; ++z) a3[z] = 0.f;
            half8 c0 = *(const half8*)(tb + (kh * 16 + 0) * 32);
            half8 c1 = *(const half8*)(tb + (kh * 16 + 1) * 32);
            #pragma unroll 1
            for (int ks = 0; ks < 16; ++ks) {
                half8 nx = c1;
                if (ks < 14) nx = *(const half8*)(tb + (kh * 16 + ks + 2) * 32);
                const int kk = kh * 16 + ks;
                half8 a = *(const half8*)&P[m * PW + kk * 32 + quad * 8];
                a3 = __builtin_amdgcn_mfma_f32_16x16x32_f16(a, c0, a3, 0, 0, 0);
                c0 = c1; c1 = nx;
            }
            #pragma unroll
            for (int rr = 0; rr < 4; ++rr)
                rpar[kh][quad * 4 + rr][nt * 16 + m] = a3[rr];
        }
        __syncthreads();

        // ---- combine + scale -> r fp16 into Ah[:,256:384]
        #pragma unroll
        for (int half2 = 0; half2 < 2; ++half2) {
            const int e = t + half2 * 1024;
            const int row = e >> 7, dd = e & 127;
            float v = (rpar[0][row][dd] + rpar[1][row][dd]) * sinv[row];
            Ah[row * AHW + 256 + dd] = (_Float16)v;
        }
        __syncthreads();

        // ---- gates: acc = gq + [h|r] @ w_hh^T (K = 256), prefetched
        floatx4 acc[4];
        #pragma unroll
        for (int g = 0; g < 4; ++g) acc[g] = gqr[g];
        {
            const _Float16* wb = w16 + 131072 + (size_t)u * 256 + quad * 8;  // +g*256*256, +ks*32
            half8 cur[4], nxt[4];
            #pragma unroll
            for (int g = 0; g < 4; ++g) {
                cur[g] = *(const half8*)(wb + (size_t)g * 256 * 256);
                nxt[g] = h8zero();
            }
            #pragma unroll 1
            for (int ks = 0; ks < 8; ++ks) {
                if (ks < 7) {
                    #pragma unroll
                    for (int g = 0; g < 4; ++g)
                        nxt[g] = *(const half8*)(wb + (size_t)g * 256 * 256 + (ks + 1) * 32);
                }
                half8 a = *(const half8*)&Ah[m * AHW + 128 + ks * 32 + quad * 8];
                #pragma unroll
                for (int g = 0; g < 4; ++g)
                    acc[g] = __builtin_amdgcn_mfma_f32_16x16x32_f16(a, cur[g], acc[g], 0, 0, 0);
                #pragma unroll
                for (int g = 0; g < 4; ++g) cur[g] = nxt[g];
            }
        }
        __syncthreads();   // all Ah reads done before h is overwritten

        // ---- pointwise
        #pragma unroll
        for (int rr = 0; rr < 4; ++rr) {
            float gi = acc[0][rr] + bi[0];
            float gf = acc[1][rr] + bi[1];
            float gg = acc[2][rr] + bi[2];
            float go = acc[3][rr] + bi[3];
            float cn = sigmoid_f(gf) * creg[rr] + sigmoid_f(gi) * tanh_fast(gg);
            creg[rr] = cn;
            if (w < 8) {
                const int row = quad * 4 + rr;
                float ho = qF[row][u] + sigmoid_f(go) * tanh_fast(cn);
                Ah[row * AHW + 128 + u] = (_Float16)ho;
                hF[row][u] = ho;
            }
        }
        __syncthreads();
    }

    // ---- cosine: wave w -> row w
    {
        const int row = w;
        float a0 = hF[row][lane], a1 = hF[row][lane + 64];
        float s0 = sg[(b0 + row) * D + lane], s1 = sg[(b0 + row) * D + lane + 64];
        float cr = a0 * s0 + a1 * s1;
        float n1 = a0 * a0 + a1 * a1;
        float n2 = s0 * s0 + s1 * s1;
        for (int off = 32; off; off >>= 1) {
            cr += __shfl_down(cr, off);
            n1 += __shfl_down(n1, off);
            n2 += __shfl_down(n2, off);
        }
        if (lane == 0) out[b0 + row] = cr / sqrtf(n1 * n2);
    }
}

// ---------------------------------------------------------------------------
extern "C" void kernel_launch(void* const* d_in, const int* in_sizes, int n_in,
                              void* d_out, int out_size, void* d_ws, size_t ws_size,
                              hipStream_t stream)
{
    const int*   relations = (const int*)d_in[0];
    const int*   entities  = (const int*)d_in[1];
    const int*   query     = (const int*)d_in[2];
    const float* emb       = (const float*)d_in[3];
    const float* gcn_w     = (const float*)d_in[4];
    const float* gcn_b     = (const float*)d_in[5];
    const float* p1_w      = (const float*)d_in[6];
    const float* p1_b      = (const float*)d_in[7];
    const float* p2_w      = (const float*)d_in[8];
    const float* p2_b      = (const float*)d_in[9];
    const float* ln_a      = (const float*)d_in[10];
    const float* ln_b      = (const float*)d_in[11];
    const float* w_ih      = (const float*)d_in[12];
    const float* w_hh      = (const float*)d_in[13];
    const float* b_ih      = (const float*)d_in[14];
    const float* b_hh      = (const float*)d_in[15];

    // Workspace layout (float-slot offsets)
    float* ws = (float*)d_ws;
    float*     sg   = ws;                          // 131072
    float*     qb   = ws + 131072;                 // 131072
    _Float16*  sgH  = (_Float16*)(ws + 262144);    // 65536 float slots
    _Float16*  sgT  = (_Float16*)(ws + 327680);
    _Float16*  qbH  = (_Float16*)(ws + 393216);
    _Float16*  w16  = (_Float16*)(ws + 458752);    // 196608 float slots
    // end: 655360 floats = 2.6 MB

    k_support<<<dim3(B_SZ), dim3(512), 0, stream>>>(
        relations, entities, query, emb, gcn_w, gcn_b,
        p1_w, p1_b, p2_w, p2_b, ln_a, ln_b,
        w_ih, w_hh, w16,
        sg, sgH, sgT, qb, qbH);
    k_lstm<<<dim3(64), dim3(1024), 0, stream>>>(
        qbH, qb, sgH, sgT, sg, w16, b_ih, b_hh, (float*)d_out);
}

// Round 7
// 328.023 us; speedup vs baseline: 1.0278x; 1.0278x over previous
//
#include <hip/hip_runtime.h>
#include <math.h>

#define D 128
#define B_SZ 1024
#define KNB 200
#define AHW 392   // [q|h|r] LDS stride (halves): 196 dw, %32=4 -> cheap 2-way pairs
#define PW 1048   // P LDS stride (halves)

typedef _Float16 half8 __attribute__((ext_vector_type(8)));
typedef float floatx4 __attribute__((ext_vector_type(4)));

__device__ __forceinline__ float sigmoid_f(float x) { return 1.f / (1.f + __expf(-x)); }
__device__ __forceinline__ float tanh_fast(float x) { return 1.f - 2.f / (__expf(2.f * x) + 1.f); }

__device__ __forceinline__ half8 h8zero() {
    half8 z;
    #pragma unroll
    for (int i = 0; i < 8; ++i) z[i] = (_Float16)0.f;
    return z;
}

// ---------------------------------------------------------------------------
// Kernel 1: gather+sum, GCN linear, support encoder, query gather.
// One block per batch row b, 512 threads. (Known wall: ~1.25 TB/s random.)
// Blocks 0..95 additionally convert the LSTM weights to fp16:
// w16[0:131072] = w_ih [1024][128]; w16[131072:] = w_hh [1024][256].
// ---------------------------------------------------------------------------
__global__ __launch_bounds__(512) void k_support(
    const int* __restrict__ relations, const int* __restrict__ entities,
    const int* __restrict__ query, const float* __restrict__ emb,
    const float* __restrict__ gcn_w, const float* __restrict__ gcn_b,
    const float* __restrict__ p1_w, const float* __restrict__ p1_b,
    const float* __restrict__ p2_w, const float* __restrict__ p2_b,
    const float* __restrict__ ln_a, const float* __restrict__ ln_b,
    const float* __restrict__ w_ih, const float* __restrict__ w_hh,
    _Float16* __restrict__ w16,
    float* __restrict__ sg, _Float16* __restrict__ sgH, _Float16* __restrict__ sgT,
    float* __restrict__ qb, _Float16* __restrict__ qbH)
{
    __shared__ int idxs[2 * KNB];
    __shared__ __align__(16) float part[16][132];
    __shared__ __align__(16) float S[2 * D];
    __shared__ __align__(16) float sup[D];
    __shared__ __align__(16) float hid[2 * D];
    __shared__ __align__(16) float zv[D];
    __shared__ float red2[2];

    const int b = blockIdx.x;
    const int t = threadIdx.x;

    // ---- folded weight conversion (96 blocks x 512 thr x 8 floats = 393216)
    if (b < 96) {
        const int i8 = (b * 512 + t) * 8;
        const float* src = (i8 < 131072) ? (w_ih + i8) : (w_hh + (i8 - 131072));
        float4 v0 = *(const float4*)src;
        float4 v1 = *(const float4*)(src + 4);
        half8 h;
        h[0] = (_Float16)v0.x; h[1] = (_Float16)v0.y; h[2] = (_Float16)v0.z; h[3] = (_Float16)v0.w;
        h[4] = (_Float16)v1.x; h[5] = (_Float16)v1.y; h[6] = (_Float16)v1.z; h[7] = (_Float16)v1.w;
        *(half8*)&w16[i8] = h;
    }

    if (t < KNB) idxs[t] = relations[b * KNB + t];
    else if (t < 2 * KNB) idxs[t] = entities[b * KNB + (t - KNB)];
    __syncthreads();

    {
        const int g = t >> 5, c4 = (t & 31) * 4;
        const int* mi = &idxs[(g >> 3) * KNB];
        float4 a4 = make_float4(0.f, 0.f, 0.f, 0.f);
        #pragma unroll 5
        for (int k = (g & 7); k < KNB; k += 8) {
            float4 v = *(const float4*)&emb[(size_t)mi[k] * D + c4];
            a4.x += v.x; a4.y += v.y; a4.z += v.z; a4.w += v.w;
        }
        *(float4*)&part[g][c4] = a4;
    }
    __syncthreads();
    if (t < 2 * D) {
        const int half = t >> 7, c = t & 127;
        float s = 0.f;
        #pragma unroll
        for (int j = 0; j < 8; ++j) s += part[half * 8 + j][c];
        S[t] = s;
    }
    __syncthreads();

    if (t < D) {
        const float4* w4 = (const float4*)(gcn_w + t * 2 * D);
        float dot = 0.f;
        #pragma unroll 8
        for (int f = 0; f < 2 * D / 4; ++f) {
            float4 w = w4[f];
            float4 s = *(const float4*)&S[f * 4];
            dot += w.x * s.x + w.y * s.y + w.z * s.z + w.w * s.w;
        }
        float v = (dot + 200.f * gcn_b[t]) * (1.f / 1024.f);  // num_neighbors = B = 1024
        sup[t] = tanhf(v);
    }
    __syncthreads();

    if (t < 2 * D) {
        const float4* w4 = (const float4*)(p1_w + t * D);
        float dot = 0.f;
        #pragma unroll 8
        for (int f = 0; f < D / 4; ++f) {
            float4 w = w4[f];
            float4 s = *(const float4*)&sup[f * 4];
            dot += w.x * s.x + w.y * s.y + w.z * s.z + w.w * s.w;
        }
        float h = dot + p1_b[t];
        hid[t] = h > 0.f ? h : 0.f;
    }
    __syncthreads();

    if (t < D) {
        const float4* w4 = (const float4*)(p2_w + t * 2 * D);
        float dot = 0.f;
        #pragma unroll 8
        for (int f = 0; f < 2 * D / 4; ++f) {
            float4 w = w4[f];
            float4 s = *(const float4*)&hid[f * 4];
            dot += w.x * s.x + w.y * s.y + w.z * s.z + w.w * s.w;
        }
        zv[t] = dot + p2_b[t] + sup[t];
    }
    __syncthreads();

    if (t < 64) {
        float x0 = zv[t], x1 = zv[t + 64];
        float s = x0 + x1;
        for (int off = 32; off; off >>= 1) s += __shfl_down(s, off);
        float mu = __shfl(s, 0) * (1.f / 128.f);
        float d0 = x0 - mu, d1 = x1 - mu;
        float v = d0 * d0 + d1 * d1;
        for (int off = 32; off; off >>= 1) v += __shfl_down(v, off);
        v = __shfl(v, 0);
        if (t == 0) { red2[0] = mu; red2[1] = sqrtf(v * (1.f / 127.f)); }
    }
    __syncthreads();
    if (t < D) {
        float mu = red2[0], sigma = red2[1];
        float val = (zv[t] - mu) / (sigma + 1e-3f) * ln_a[t] + ln_b[t];
        sg[b * D + t] = val;
        sgH[b * D + t] = (_Float16)val;
        sgT[t * B_SZ + b] = (_Float16)val;
        float qv = emb[(size_t)query[b] * D + t];
        qb[b * D + t] = qv;
        qbH[b * D + t] = (_Float16)qv;
    }
}

// ---------------------------------------------------------------------------
// Kernel 2: FUSED recurrence, re-tiled for CU coverage.
// 128 blocks x 8 batch rows, 512 threads (8 waves). r6 postmortem: phases are
// latency-bound; 64-block tiling engaged only 64 CUs (4x fewer SIMDs than the
// unfused r0 pipeline whose identical phase work summed to ~84us). This
// version: 2x CUs, half the per-block work, 8-wave barriers, 5 barriers/step.
// Register discipline (allocator caps at 64 and spills rather than exceed —
// r3/r4/r6 evidence): single K=384 gates GEMM ([q|h|r], q-part recomputed per
// step, no persistent gqr), fully-unrolled g / hv for static acc indexing,
// per-g K-loops with depth-1 prefetch (8 B-regs in flight), r full-K per wave
// (no rpar/combine), softmax via per-wave shfl + redundant all-wave reduce
// (no serial t<16 sections). MFMA M-tiles carry 8 valid rows (rows 8-15 of
// Ah/P zeroed once).
// ---------------------------------------------------------------------------
__global__ __launch_bounds__(512)
void k_lstm(
    const _Float16* __restrict__ qbH, const float* __restrict__ qb,
    const _Float16* __restrict__ sgH, const _Float16* __restrict__ sgT,
    const float* __restrict__ sg, const _Float16* __restrict__ w16,
    const float* __restrict__ b_ih, const float* __restrict__ b_hh,
    float* __restrict__ out)
{
    __shared__ _Float16 Ah[16 * AHW];   // rows 0-7 live, 8-15 zero; [0:128]=q,[128:256]=h,[256:384]=r
    __shared__ _Float16 P[16 * PW];     // rows 8-15 zero
    __shared__ float qF[8][132];
    __shared__ float hF[8][132];
    __shared__ float pm[8][12];         // per-wave row-max partials
    __shared__ float ps[8][12];         // per-wave row-sum partials

    const int t = threadIdx.x;          // 0..511
    const int w = t >> 6, lane = t & 63;
    const int m = lane & 15, quad = lane >> 4;
    const int b0 = blockIdx.x * 8;

    // ---- prologue: zero Ah (all) and P rows 8..15, then stage q
    for (int i = t; i < 16 * AHW / 8; i += 512) *(half8*)&Ah[i * 8] = h8zero();
    for (int i = t; i < 8 * PW / 8; i += 512) *(half8*)&P[8 * PW + i * 8] = h8zero();
    __syncthreads();
    if (t < 128) {
        const int row = t >> 4, c = (t & 15) * 8;
        *(half8*)&Ah[row * AHW + c] = *(const half8*)&qbH[(size_t)(b0 + row) * D + c];
    }
    if (t < 256) {
        const int row = t >> 5, c = (t & 31) * 4;
        *(float4*)&qF[row][c] = *(const float4*)&qb[(size_t)(b0 + row) * D + c];
    }
    __syncthreads();

    float cregA[4] = {0.f, 0.f, 0.f, 0.f};   // c for units w*16+m
    float cregB[4] = {0.f, 0.f, 0.f, 0.f};   // c for units (w+8)*16+m

    #pragma unroll 1
    for (int s = 0; s < 4; ++s) {
        if (s > 0) {
            // ---- scores: wave w -> j-tiles w*8 .. w*8+7 (128 j's), rows 0-7 valid
            floatx4 a2[8];
            #pragma unroll
            for (int i = 0; i < 8; ++i)
                #pragma unroll
                for (int z = 0; z < 4; ++z) a2[i][z] = 0.f;
            #pragma unroll 1
            for (int ks = 0; ks < 4; ++ks) {
                half8 a = *(const half8*)&Ah[m * AHW + 128 + ks * 32 + quad * 8];
                const _Float16* sb = sgH + (size_t)m * D + ks * 32 + quad * 8;
                #pragma unroll
                for (int g4 = 0; g4 < 2; ++g4) {
                    half8 b0v = *(const half8*)(sb + (size_t)((w * 8 + g4 * 4 + 0) * 16) * D);
                    half8 b1v = *(const half8*)(sb + (size_t)((w * 8 + g4 * 4 + 1) * 16) * D);
                    half8 b2v = *(const half8*)(sb + (size_t)((w * 8 + g4 * 4 + 2) * 16) * D);
                    half8 b3v = *(const half8*)(sb + (size_t)((w * 8 + g4 * 4 + 3) * 16) * D);
                    a2[g4 * 4 + 0] = __builtin_amdgcn_mfma_f32_16x16x32_f16(a, b0v, a2[g4 * 4 + 0], 0, 0, 0);
                    a2[g4 * 4 + 1] = __builtin_amdgcn_mfma_f32_16x16x32_f16(a, b1v, a2[g4 * 4 + 1], 0, 0, 0);
                    a2[g4 * 4 + 2] = __builtin_amdgcn_mfma_f32_16x16x32_f16(a, b2v, a2[g4 * 4 + 2], 0, 0, 0);
                    a2[g4 * 4 + 3] = __builtin_amdgcn_mfma_f32_16x16x32_f16(a, b3v, a2[g4 * 4 + 3], 0, 0, 0);
                }
            }

            // ---- per-wave row-max over this wave's 128 j's
            float mx[4];
            #pragma unroll
            for (int rr = 0; rr < 4; ++rr) {
                float v0 = fmaxf(fmaxf(a2[0][rr], a2[1][rr]), fmaxf(a2[2][rr], a2[3][rr]));
                float v1 = fmaxf(fmaxf(a2[4][rr], a2[5][rr]), fmaxf(a2[6][rr], a2[7][rr]));
                mx[rr] = fmaxf(v0, v1);
            }
            #pragma unroll
            for (int off = 1; off <= 8; off <<= 1)
                #pragma unroll
                for (int rr = 0; rr < 4; ++rr)
                    mx[rr] = fmaxf(mx[rr], __shfl_xor(mx[rr], off));
            if (m == 0) {
                #pragma unroll
                for (int rr = 0; rr < 4; ++rr) {
                    const int row = quad * 4 + rr;
                    if (row < 8) pm[w][row] = mx[rr];
                }
            }
            __syncthreads();   // BAR1

            // ---- global row-max (redundant per lane), exp, P write, sum partials
            float gm[4];
            #pragma unroll
            for (int rr = 0; rr < 4; ++rr) {
                const int row = quad * 4 + rr;
                float mm = -1e30f;
                if (row < 8) {
                    #pragma unroll
                    for (int ww = 0; ww < 8; ++ww) mm = fmaxf(mm, pm[ww][row]);
                }
                gm[rr] = mm;
            }
            float sl[4] = {0.f, 0.f, 0.f, 0.f};
            #pragma unroll
            for (int i = 0; i < 8; ++i) {
                const int col = (w * 8 + i) * 16 + m;
                #pragma unroll
                for (int rr = 0; rr < 4; ++rr) {
                    const int row = quad * 4 + rr;
                    if (row < 8) {
                        float e = __expf(a2[i][rr] - gm[rr]);
                        P[row * PW + col] = (_Float16)e;
                        sl[rr] += e;
                    }
                }
            }
            #pragma unroll
            for (int off = 1; off <= 8; off <<= 1)
                #pragma unroll
                for (int rr = 0; rr < 4; ++rr)
                    sl[rr] += __shfl_xor(sl[rr], off);
            if (m == 0) {
                #pragma unroll
                for (int rr = 0; rr < 4; ++rr) {
                    const int row = quad * 4 + rr;
                    if (row < 8) ps[w][row] = sl[rr];
                }
            }
            __syncthreads();   // BAR2

            // ---- sinv (redundant per lane)
            float sinvd[4];
            #pragma unroll
            for (int rr = 0; rr < 4; ++rr) {
                const int row = quad * 4 + rr;
                float ss = 1.f;
                if (row < 8) {
                    ss = 0.f;
                    #pragma unroll
                    for (int ww = 0; ww < 8; ++ww) ss += ps[ww][row];
                }
                sinvd[rr] = 1.f / ss;
            }

            // ---- r: wave w computes col-tile w (cols w*16..+15), full K=1024
            {
                floatx4 a3;
                #pragma unroll
                for (int z = 0; z < 4; ++z) a3[z] = 0.f;
                const _Float16* tb = sgT + (size_t)(w * 16 + m) * B_SZ + quad * 8;
                half8 c0 = *(const half8*)(tb);
                half8 c1 = *(const half8*)(tb + 32);
                #pragma unroll 1
                for (int ks = 0; ks < 32; ++ks) {
                    half8 nx = c1;
                    if (ks < 30) nx = *(const half8*)(tb + (ks + 2) * 32);
                    half8 a = *(const half8*)&P[m * PW + ks * 32 + quad * 8];
                    a3 = __builtin_amdgcn_mfma_f32_16x16x32_f16(a, c0, a3, 0, 0, 0);
                    c0 = c1; c1 = nx;
                }
                #pragma unroll
                for (int rr = 0; rr < 4; ++rr) {
                    const int row = quad * 4 + rr;
                    if (row < 8)
                        Ah[row * AHW + 256 + w * 16 + m] = (_Float16)(a3[rr] * sinvd[rr]);
                }
            }
            __syncthreads();   // BAR3 (r visible to gates)
        }

        // ---- gates: acc = [q|h|r] @ [w_ih|w_hh]^T (K=384), two u-halves
        float hreg[4] = {0.f, 0.f, 0.f, 0.f};
        auto gates_half = [&](int v, float* cregH, bool wantH) {
            floatx4 acc[4];
            #pragma unroll
            for (int g = 0; g < 4; ++g) {
                floatx4 ac;
                #pragma unroll
                for (int z = 0; z < 4; ++z) ac[z] = 0.f;
                const _Float16* wb0 = w16 + (size_t)(g * 256 + v * 16 + m) * 128 + quad * 8;
                const _Float16* wb1 = w16 + 131072 + (size_t)(g * 256 + v * 16 + m) * 256 + quad * 8;
                half8 cur = *(const half8*)wb0;   // ks = 0
                #pragma unroll 1
                for (int ks = 0; ks < 12; ++ks) {
                    half8 nxt = cur;
                    if (ks < 3)       nxt = *(const half8*)(wb0 + (ks + 1) * 32);
                    else if (ks < 11) nxt = *(const half8*)(wb1 + (ks - 3) * 32);
                    half8 a = *(const half8*)&Ah[m * AHW + ks * 32 + quad * 8];
                    ac = __builtin_amdgcn_mfma_f32_16x16x32_f16(a, cur, ac, 0, 0, 0);
                    cur = nxt;
                }
                acc[g] = ac;
            }
            const int unit = v * 16 + m;
            float bi0 = b_ih[unit] + b_hh[unit];
            float bi1 = b_ih[256 + unit] + b_hh[256 + unit];
            float bi2 = b_ih[512 + unit] + b_hh[512 + unit];
            float bi3 = b_ih[768 + unit] + b_hh[768 + unit];
            #pragma unroll
            for (int rr = 0; rr < 4; ++rr) {
                float gi = acc[0][rr] + bi0;
                float gf = acc[1][rr] + bi1;
                float gg = acc[2][rr] + bi2;
                float go = acc[3][rr] + bi3;
                float cn = sigmoid_f(gf) * cregH[rr] + sigmoid_f(gi) * tanh_fast(gg);
                cregH[rr] = cn;
                if (wantH) hreg[rr] = sigmoid_f(go) * tanh_fast(cn);
            }
        };
        gates_half(w, cregA, true);        // units w*16+m  (h-range, unit<128)
        gates_half(w + 8, cregB, false);   // units (w+8)*16+m
        __syncthreads();   // BAR4: all Ah reads (q|h|r) complete

        // ---- h write (h_out = q + h[:,:D]); unit = w*16+m covers 0..127
        {
            const int unit = w * 16 + m;
            #pragma unroll
            for (int rr = 0; rr < 4; ++rr) {
                const int row = quad * 4 + rr;
                if (row < 8) {
                    float ho = qF[row][unit] + hreg[rr];
                    Ah[row * AHW + 128 + unit] = (_Float16)ho;
                    hF[row][unit] = ho;
                }
            }
        }
        __syncthreads();   // BAR5: new h visible
    }

    // ---- cosine: wave w -> row w (8 rows)
    {
        const int row = w;
        float a0 = hF[row][lane], a1 = hF[row][lane + 64];
        float s0 = sg[(size_t)(b0 + row) * D + lane], s1 = sg[(size_t)(b0 + row) * D + lane + 64];
        float cr = a0 * s0 + a1 * s1;
        float n1 = a0 * a0 + a1 * a1;
        float n2 = s0 * s0 + s1 * s1;
        for (int off = 32; off; off >>= 1) {
            cr += __shfl_down(cr, off);
            n1 += __shfl_down(n1, off);
            n2 += __shfl_down(n2, off);
        }
        if (lane == 0) out[b0 + row] = cr / sqrtf(n1 * n2);
    }
}

// ---------------------------------------------------------------------------
extern "C" void kernel_launch(void* const* d_in, const int* in_sizes, int n_in,
                              void* d_out, int out_size, void* d_ws, size_t ws_size,
                              hipStream_t stream)
{
    const int*   relations = (const int*)d_in[0];
    const int*   entities  = (const int*)d_in[1];
    const int*   query     = (const int*)d_in[2];
    const float* emb       = (const float*)d_in[3];
    const float* gcn_w     = (const float*)d_in[4];
    const float* gcn_b     = (const float*)d_in[5];
    const float* p1_w      = (const float*)d_in[6];
    const float* p1_b      = (const float*)d_in[7];
    const float* p2_w      = (const float*)d_in[8];
    const float* p2_b      = (const float*)d_in[9];
    const float* ln_a      = (const float*)d_in[10];
    const float* ln_b      = (const float*)d_in[11];
    const float* w_ih      = (const float*)d_in[12];
    const float* w_hh      = (const float*)d_in[13];
    const float* b_ih      = (const float*)d_in[14];
    const float* b_hh      = (const float*)d_in[15];

    // Workspace layout (float-slot offsets)
    float* ws = (float*)d_ws;
    float*     sg   = ws;                          // 131072
    float*     qb   = ws + 131072;                 // 131072
    _Float16*  sgH  = (_Float16*)(ws + 262144);    // 65536 float slots
    _Float16*  sgT  = (_Float16*)(ws + 327680);
    _Float16*  qbH  = (_Float16*)(ws + 393216);
    _Float16*  w16  = (_Float16*)(ws + 458752);    // 196608 float slots
    // end: 655360 floats = 2.6 MB

    k_support<<<dim3(B_SZ), dim3(512), 0, stream>>>(
        relations, entities, query, emb, gcn_w, gcn_b,
        p1_w, p1_b, p2_w, p2_b, ln_a, ln_b,
        w_ih, w_hh, w16,
        sg, sgH, sgT, qb, qbH);
    k_lstm<<<dim3(B_SZ / 8), dim3(512), 0, stream>>>(
        qbH, qb, sgH, sgT, sg, w16, b_ih, b_hh, (float*)d_out);
}